// Round 10
// baseline (166.804 us; speedup 1.0000x reference)
//
#include <hip/hip_runtime.h>

#define FEAT_DIM 256
#define K_NEIGH  32
#define NROWS    20480   // B*S = 2048*10
#define NOUT     1024    // CLIPS*DIM = 8*128
#define NUM_NODES 50000
#define SLICE_DIM 32
#define NSLICE    8
#define FBLK      1563   // ceil(NUM_NODES/32)
#define MT        32     // fused M-tile rows per block

typedef __attribute__((ext_vector_type(8))) short bf16x8;
typedef __attribute__((ext_vector_type(4))) float f32x4;
typedef __attribute__((ext_vector_type(4))) int   i32x4;

__device__ __forceinline__ unsigned short f2bf(float f) {
    unsigned int u = __builtin_bit_cast(unsigned int, f);
    u += 0x7fffu + ((u >> 16) & 1u);
    return (unsigned short)(u >> 16);
}
__device__ __forceinline__ float bf2f(unsigned short h) {
    unsigned int u = ((unsigned int)h) << 16;
    return __builtin_bit_cast(float, u);
}

// ---- weight-only convert (fallback path) ------------------------------------
__global__ __launch_bounds__(256) void wcvt_kernel(const float* __restrict__ w,
                                                   unsigned short* __restrict__ wb) {
    int i = (blockIdx.x * 256 + threadIdx.x) * 4;
    float4 v = *(const float4*)(w + i);
    ushort4 o;
    o.x = f2bf(v.x); o.y = f2bf(v.y); o.z = f2bf(v.z); o.w = f2bf(v.w);
    *(ushort4*)(wb + i) = o;
}

// ---- convert: features -> fb[8][50000][32] bf16  +  W -> bf16 ---------------
__global__ __launch_bounds__(256) void cvt_kernel(const float* __restrict__ f,
                                                  unsigned short* __restrict__ fb,
                                                  const float* __restrict__ w,
                                                  unsigned short* __restrict__ wb) {
    int b = blockIdx.x;
    int t = threadIdx.x;
    if (b < FBLK) {
        int g = t >> 5;            // slice 0..7
        int i = t & 31;            // node offset
        int node = b * 32 + i;
        if (node >= NUM_NODES) return;
        const float* src = f + (long)node * FEAT_DIM + g * SLICE_DIM;
        unsigned short o[32];
        #pragma unroll
        for (int j = 0; j < 32; j += 4) {
            float4 v = *(const float4*)(src + j);
            o[j] = f2bf(v.x); o[j+1] = f2bf(v.y); o[j+2] = f2bf(v.z); o[j+3] = f2bf(v.w);
        }
        unsigned short* dst = fb + ((long)g * NUM_NODES + node) * SLICE_DIM;
        #pragma unroll
        for (int j = 0; j < 4; ++j)
            *(bf16x8*)(dst + j * 8) = *(const bf16x8*)(o + j * 8);
    } else {
        int i = ((b - FBLK) * 256 + t) * 4;
        float4 v = *(const float4*)(w + i);
        ushort4 o;
        o.x = f2bf(v.x); o.y = f2bf(v.y); o.z = f2bf(v.z); o.w = f2bf(v.w);
        *(ushort4*)(wb + i) = o;
    }
}

// ---- FUSED agg + GEMM: block = 32 rows, full 1024-col output ----------------
// Phase 1: thread (row=t>>3, slice=t&7) gathers 32 nbrs x 32 dims -> LDS A-tile
//          (XOR-swizzled rows to kill D=256 bank conflicts).
// Phase 2: 4 waves, wave w computes out[32][w*256..w*256+256) via MFMA,
//          A from LDS, W (bf16, row-major [1024][256]) from L2.
__global__ __launch_bounds__(256) void fused_kernel(const int* __restrict__ nodes,
                                                    const int* __restrict__ adj,
                                                    const unsigned short* __restrict__ fb,
                                                    const unsigned short* __restrict__ wb,
                                                    float* __restrict__ C) {
    __shared__ short As[MT * FEAT_DIM];   // 16 KB

    int t = threadIdx.x;
    int m0 = blockIdx.x * MT;

    // ---------------- gather + aggregate ----------------
    {
        int row = t >> 3;              // 0..31
        int slice = t & 7;             // 0..7
        int node = nodes[m0 + row];    // 8 lanes same addr -> coalescer dedup
        const int* arow = adj + (long)node * K_NEIGH;
        int nbr[K_NEIGH];
        #pragma unroll
        for (int kk = 0; kk < K_NEIGH / 4; ++kk) {
            i32x4 q = *(const i32x4*)(arow + kk * 4);
            nbr[kk*4] = q.x; nbr[kk*4+1] = q.y; nbr[kk*4+2] = q.z; nbr[kk*4+3] = q.w;
        }
        const unsigned short* base = fb + (long)slice * NUM_NODES * SLICE_DIM;
        float acc[32] = {};
        #pragma unroll 4
        for (int k = 0; k < K_NEIGH; ++k) {
            const unsigned short* p = base + (long)nbr[k] * SLICE_DIM;
            #pragma unroll
            for (int q4 = 0; q4 < 4; ++q4) {           // 4x16B = one 64B granule
                bf16x8 v = *(const bf16x8*)(p + q4 * 8);
                #pragma unroll
                for (int j = 0; j < 8; ++j) acc[q4 * 8 + j] += bf2f((unsigned short)v[j]);
            }
        }
        char* rowp = (char*)As + row * (FEAT_DIM * 2);
        #pragma unroll
        for (int q4 = 0; q4 < 4; ++q4) {
            unsigned short o[8];
            #pragma unroll
            for (int j = 0; j < 8; ++j) o[j] = f2bf(acc[q4 * 8 + j] * (1.0f / K_NEIGH));
            int byte_in_row = (slice * 64 + q4 * 16) ^ ((row & 7) << 4);   // swizzle
            *(bf16x8*)(rowp + byte_in_row) = *(const bf16x8*)o;
        }
    }
    __syncthreads();

    // ---------------- GEMM ----------------
    int wave = t >> 6, lane = t & 63;
    int lr = lane & 15;
    int lk = (lane >> 4) * 8;
    const short* Bg = (const short*)wb + (long)(wave * 256 + lr) * FEAT_DIM + lk;

    f32x4 acc2[2][16] = {};
    #pragma unroll
    for (int kb = 0; kb < FEAT_DIM; kb += 32) {
        bf16x8 a[2];
        #pragma unroll
        for (int mf = 0; mf < 2; ++mf) {
            int row = mf * 16 + lr;
            int byte_in_row = ((kb + lk) * 2) ^ ((row & 7) << 4);          // swizzle
            a[mf] = *(const bf16x8*)((const char*)As + row * (FEAT_DIM * 2) + byte_in_row);
        }
        #pragma unroll
        for (int nf = 0; nf < 16; ++nf) {
            bf16x8 b = *(const bf16x8*)(Bg + (long)nf * 16 * FEAT_DIM + kb);
            acc2[0][nf] = __builtin_amdgcn_mfma_f32_16x16x32_bf16(a[0], b, acc2[0][nf], 0, 0, 0);
            acc2[1][nf] = __builtin_amdgcn_mfma_f32_16x16x32_bf16(a[1], b, acc2[1][nf], 0, 0, 0);
        }
    }

    // epilogue: C/D layout col=lane&15, row=(lane>>4)*4+reg (verified R0)
    #pragma unroll
    for (int mf = 0; mf < 2; ++mf)
        #pragma unroll
        for (int nf = 0; nf < 16; ++nf)
            #pragma unroll
            for (int r = 0; r < 4; ++r) {
                int crow = m0 + mf * 16 + (lane >> 4) * 4 + r;
                int ccol = wave * 256 + nf * 16 + lr;
                float v = acc2[mf][nf][r];
                __builtin_nontemporal_store(v > 0.f ? v : 0.f, &C[(long)crow * NOUT + ccol]);
            }
}

// ---- fallback path (small ws): fp32 agg + standalone gemm ------------------
__global__ __launch_bounds__(256) void agg_f32_kernel(const int* __restrict__ nodes,
                                                      const int* __restrict__ adj,
                                                      const float* __restrict__ features,
                                                      unsigned short* __restrict__ feat) {
    int row = blockIdx.x;
    int t = threadIdx.x;
    int node = nodes[row];
    const int* arow = adj + (long)node * K_NEIGH;
    float acc = 0.f;
    #pragma unroll
    for (int k = 0; k < K_NEIGH; ++k) {
        long nb = arow[k];
        acc += features[nb * FEAT_DIM + t];
    }
    feat[(long)row * FEAT_DIM + t] = f2bf(acc * (1.0f / K_NEIGH));
}

__global__ __launch_bounds__(256) void gemm_kernel(const unsigned short* __restrict__ A,
                                                   const unsigned short* __restrict__ Bw,
                                                   float* __restrict__ C) {
    __shared__ short As2[128 * 32];
    __shared__ short Bs2[128 * 32];
    int t = threadIdx.x;
    int wave = t >> 6, lane = t & 63;
    int wm = wave >> 1, wn = wave & 1;
    int m0 = blockIdx.x * 128, n0 = blockIdx.y * 128;
    int lr = lane & 15, lk = (lane >> 4) * 8;
    int srow = t >> 2, sseg = (t & 3) * 8;
    const short* Ag = (const short*)A + (long)(m0 + srow) * FEAT_DIM + sseg;
    const short* Bg = (const short*)Bw + (long)(n0 + srow) * FEAT_DIM + sseg;
    f32x4 acc[4][4] = {};
    for (int kb = 0; kb < FEAT_DIM; kb += 32) {
        if (kb) __syncthreads();
        *(bf16x8*)&As2[t * 8] = *(const bf16x8*)(Ag + kb);
        *(bf16x8*)&As2[64 * 32 + t * 8] = *(const bf16x8*)(Ag + 64 * FEAT_DIM + kb);
        *(bf16x8*)&Bs2[t * 8] = *(const bf16x8*)(Bg + kb);
        *(bf16x8*)&Bs2[64 * 32 + t * 8] = *(const bf16x8*)(Bg + 64 * FEAT_DIM + kb);
        __syncthreads();
        bf16x8 a[4], b[4];
        #pragma unroll
        for (int i = 0; i < 4; ++i)
            a[i] = *(const bf16x8*)(&As2[(wm * 64 + i * 16 + lr) * 32 + lk]);
        #pragma unroll
        for (int j = 0; j < 4; ++j)
            b[j] = *(const bf16x8*)(&Bs2[(wn * 64 + j * 16 + lr) * 32 + lk]);
        #pragma unroll
        for (int i = 0; i < 4; ++i)
            #pragma unroll
            for (int j = 0; j < 4; ++j)
                acc[i][j] = __builtin_amdgcn_mfma_f32_16x16x32_bf16(a[i], b[j], acc[i][j], 0, 0, 0);
    }
    int crow0 = m0 + wm * 64 + (lane >> 4) * 4;
    int ccol0 = n0 + wn * 64 + lr;
    #pragma unroll
    for (int i = 0; i < 4; ++i)
        #pragma unroll
        for (int j = 0; j < 4; ++j)
            #pragma unroll
            for (int r = 0; r < 4; ++r) {
                float v = acc[i][j][r];
                C[(long)(crow0 + i * 16 + r) * NOUT + ccol0 + j * 16] = v > 0.f ? v : 0.f;
            }
}

extern "C" void kernel_launch(void* const* d_in, const int* in_sizes, int n_in,
                              void* d_out, int out_size, void* d_ws, size_t ws_size,
                              hipStream_t stream) {
    const int*   nodes    = (const int*)d_in[0];
    const int*   adj      = (const int*)d_in[1];
    const float* features = (const float*)d_in[2];
    const float* lw       = (const float*)d_in[3];
    float*       out      = (float*)d_out;

    const size_t fbf_elems  = (size_t)NUM_NODES * FEAT_DIM;
    const size_t wb_elems   = (size_t)NOUT * FEAT_DIM;
    const size_t feat_elems = (size_t)NROWS * FEAT_DIM;
    const size_t need = (fbf_elems + wb_elems) * 2;

    if (ws_size >= need) {
        unsigned short* fbf = (unsigned short*)d_ws;
        unsigned short* wb  = fbf + fbf_elems;

        cvt_kernel<<<FBLK + (NOUT * FEAT_DIM) / (256 * 4), 256, 0, stream>>>(features, fbf, lw, wb);
        fused_kernel<<<NROWS / MT, 256, 0, stream>>>(nodes, adj, fbf, wb, out);
    } else {
        unsigned short* feat = (unsigned short*)d_ws;
        unsigned short* wb   = feat + feat_elems;

        wcvt_kernel<<<(NOUT * FEAT_DIM) / (256 * 4), 256, 0, stream>>>(lw, wb);
        agg_f32_kernel<<<NROWS, 256, 0, stream>>>(nodes, adj, features, feat);
        gemm_kernel<<<dim3(NROWS / 128, NOUT / 128), 256, 0, stream>>>(feat, wb, out);
    }
}

// Round 11
// 83.589 us; speedup vs baseline: 1.9955x; 1.9955x over previous
//
#include <hip/hip_runtime.h>

#define FEAT_DIM 256
#define K_NEIGH  32
#define NROWS    20480   // B*S = 2048*10
#define NOUT     1024    // CLIPS*DIM = 8*128
#define NUM_NODES 50000
#define SLICE_DIM 32
#define NSLICE    8
#define FBLK      1563   // ceil(NUM_NODES/32)

typedef __attribute__((ext_vector_type(8))) short bf16x8;
typedef __attribute__((ext_vector_type(4))) float f32x4;
typedef __attribute__((ext_vector_type(4))) int   i32x4;

__device__ __forceinline__ unsigned short f2bf(float f) {
    unsigned int u = __builtin_bit_cast(unsigned int, f);
    u += 0x7fffu + ((u >> 16) & 1u);
    return (unsigned short)(u >> 16);
}
__device__ __forceinline__ float bf2f(unsigned short h) {
    unsigned int u = ((unsigned int)h) << 16;
    return __builtin_bit_cast(float, u);
}
__device__ __forceinline__ void gload16(const void* g, void* l) {
    __builtin_amdgcn_global_load_lds(
        (const __attribute__((address_space(1))) unsigned int*)g,
        (__attribute__((address_space(3))) unsigned int*)l, 16, 0, 0);
}

// ---- weight-only convert (fallback path) ------------------------------------
__global__ __launch_bounds__(256) void wcvt_kernel(const float* __restrict__ w,
                                                   unsigned short* __restrict__ wb) {
    int i = (blockIdx.x * 256 + threadIdx.x) * 4;
    float4 v = *(const float4*)(w + i);
    ushort4 o;
    o.x = f2bf(v.x); o.y = f2bf(v.y); o.z = f2bf(v.z); o.w = f2bf(v.w);
    *(ushort4*)(wb + i) = o;
}

// ---- convert: features -> fb[8][50000][32] bf16  +  W -> bf16 ---------------
__global__ __launch_bounds__(256) void cvt_kernel(const float* __restrict__ f,
                                                  unsigned short* __restrict__ fb,
                                                  const float* __restrict__ w,
                                                  unsigned short* __restrict__ wb) {
    int b = blockIdx.x;
    int t = threadIdx.x;
    if (b < FBLK) {
        int g = t >> 5;            // slice 0..7
        int i = t & 31;            // node offset
        int node = b * 32 + i;
        if (node >= NUM_NODES) return;
        const float* src = f + (long)node * FEAT_DIM + g * SLICE_DIM;
        unsigned short o[32];
        #pragma unroll
        for (int j = 0; j < 32; j += 4) {
            float4 v = *(const float4*)(src + j);
            o[j] = f2bf(v.x); o[j+1] = f2bf(v.y); o[j+2] = f2bf(v.z); o[j+3] = f2bf(v.w);
        }
        unsigned short* dst = fb + ((long)g * NUM_NODES + node) * SLICE_DIM;
        #pragma unroll
        for (int j = 0; j < 4; ++j)
            *(bf16x8*)(dst + j * 8) = *(const bf16x8*)(o + j * 8);
    } else {
        int i = ((b - FBLK) * 256 + t) * 4;
        float4 v = *(const float4*)(w + i);
        ushort4 o;
        o.x = f2bf(v.x); o.y = f2bf(v.y); o.z = f2bf(v.z); o.w = f2bf(v.w);
        *(ushort4*)(wb + i) = o;
    }
}

// ---- agg, XCD-sliced (frozen at R4 — measured 43.5 us, at gather ceiling) ---
__global__ __launch_bounds__(256) void agg_sliced(const int* __restrict__ nodes,
                                                  const int* __restrict__ adj,
                                                  const unsigned short* __restrict__ fb,
                                                  unsigned short* __restrict__ feat) {
    int slice = blockIdx.x & 7;
    int chunk = blockIdx.x >> 3;
    int t = threadIdx.x;
    int row = chunk * 64 + (t >> 2);
    int d8 = (t & 3) * 8;
    int node = nodes[row];
    const int* arow = adj + (long)node * K_NEIGH;
    int nbr[K_NEIGH];
    #pragma unroll
    for (int kk = 0; kk < K_NEIGH / 4; ++kk) {
        i32x4 q = *(const i32x4*)(arow + kk * 4);
        nbr[kk*4] = q.x; nbr[kk*4+1] = q.y; nbr[kk*4+2] = q.z; nbr[kk*4+3] = q.w;
    }

    const unsigned short* base = fb + (long)slice * NUM_NODES * SLICE_DIM + d8;
    float acc[8] = {};
    #pragma unroll
    for (int k = 0; k < K_NEIGH; ++k) {
        bf16x8 v = *(const bf16x8*)(base + (long)nbr[k] * SLICE_DIM);
        #pragma unroll
        for (int j = 0; j < 8; ++j) acc[j] += bf2f((unsigned short)v[j]);
    }
    unsigned short o[8];
    #pragma unroll
    for (int j = 0; j < 8; ++j) o[j] = f2bf(acc[j] * (1.0f / K_NEIGH));
    *(bf16x8*)(feat + (long)row * FEAT_DIM + slice * SLICE_DIM + d8) = *(const bf16x8*)o;
}

// ---- agg from fp32 features (ws fallback) -----------------------------------
__global__ __launch_bounds__(256) void agg_f32_kernel(const int* __restrict__ nodes,
                                                      const int* __restrict__ adj,
                                                      const float* __restrict__ features,
                                                      unsigned short* __restrict__ feat) {
    int row = blockIdx.x;
    int t = threadIdx.x;
    int node = nodes[row];
    const int* arow = adj + (long)node * K_NEIGH;
    float acc = 0.f;
    #pragma unroll
    for (int k = 0; k < K_NEIGH; ++k) {
        long nb = arow[k];
        acc += features[nb * FEAT_DIM + t];
    }
    feat[(long)row * FEAT_DIM + t] = f2bf(acc * (1.0f / K_NEIGH));
}

// ---- GEMM: C = relu(feat x W^T); 128x128, dbuf LDS; LDS-bounce epilogue -----
// Epilogue repacks acc through LDS so every global store instruction writes
// full 128B lines (8 lanes x 16B contiguous) -> no partial-line NT RMW.
__global__ __launch_bounds__(256) void gemm_kernel(const unsigned short* __restrict__ A,
                                                   const unsigned short* __restrict__ Bw,
                                                   float* __restrict__ C) {
    __shared__ char smem[32768];
    short* As0 = (short*)smem;               // As[2][128*32]
    short* Bs0 = (short*)(smem + 16384);     // Bs[2][128*32]
    float (*Ep)[132] = (float(*)[132])smem;  // epilogue bounce [32][132] (16.9 KB)

    int bid = blockIdx.x;
    int xcd = bid & 7;
    int i2 = bid >> 3;
    int mt = xcd * 20 + (i2 % 20);
    int nt = i2 / 20;

    int t = threadIdx.x;
    int wave = t >> 6, lane = t & 63;
    int wm = wave >> 1, wn = wave & 1;
    int m0 = mt * 128, n0 = nt * 128;
    int lr = lane & 15;
    int lk = (lane >> 4) * 8;

    int srow = t >> 2;
    int sseg = (t & 3) * 8;
    const short* Ag = (const short*)A + (long)(m0 + srow) * FEAT_DIM + sseg;
    const short* Bg = (const short*)Bw + (long)(n0 + srow) * FEAT_DIM + sseg;

    f32x4 acc[4][4] = {};

#define STAGE(bufi, kb) do {                                              \
    gload16(Ag + (kb), As0 + (bufi) * 4096 + t * 8);                      \
    gload16(Ag + 64 * FEAT_DIM + (kb), As0 + (bufi) * 4096 + 64 * 32 + t * 8); \
    gload16(Bg + (kb), Bs0 + (bufi) * 4096 + t * 8);                      \
    gload16(Bg + 64 * FEAT_DIM + (kb), Bs0 + (bufi) * 4096 + 64 * 32 + t * 8); \
} while (0)

    STAGE(0, 0);
    asm volatile("s_waitcnt vmcnt(0)" ::: "memory");
    __builtin_amdgcn_s_barrier();

    #pragma unroll
    for (int it = 0; it < 8; ++it) {
        int cur = it & 1;
        if (it < 7) STAGE(cur ^ 1, (it + 1) * 32);

        bf16x8 a[4], b[4];
        #pragma unroll
        for (int i = 0; i < 4; ++i)
            a[i] = *(const bf16x8*)(As0 + cur * 4096 + (wm * 64 + i * 16 + lr) * 32 + lk);
        #pragma unroll
        for (int j = 0; j < 4; ++j)
            b[j] = *(const bf16x8*)(Bs0 + cur * 4096 + (wn * 64 + j * 16 + lr) * 32 + lk);
        #pragma unroll
        for (int i = 0; i < 4; ++i)
            #pragma unroll
            for (int j = 0; j < 4; ++j)
                acc[i][j] = __builtin_amdgcn_mfma_f32_16x16x32_bf16(a[i], b[j], acc[i][j], 0, 0, 0);

        if (it < 7) {
            asm volatile("s_waitcnt vmcnt(0)" ::: "memory");
            __builtin_amdgcn_s_barrier();
        }
    }
#undef STAGE

    // ---- epilogue: 4 chunks of 32 rows, bounce through LDS ----
    #pragma unroll
    for (int c = 0; c < 4; ++c) {
        __syncthreads();                       // previous chunk / K-loop LDS reads done
        if (wm == (c >> 1)) {
            int ibase = (c & 1) * 2;
            #pragma unroll
            for (int ii = 0; ii < 2; ++ii)
                #pragma unroll
                for (int j = 0; j < 4; ++j)
                    #pragma unroll
                    for (int r = 0; r < 4; ++r) {
                        int lrow = ii * 16 + (lane >> 4) * 4 + r;     // 0..31
                        int lcol = wn * 64 + j * 16 + lr;
                        float v = acc[ibase + ii][j][r];
                        Ep[lrow][lcol] = v > 0.f ? v : 0.f;
                    }
        }
        __syncthreads();
        int row = t >> 3;                      // 0..31
        int c4 = (t & 7) * 4;                  // float offset, 16B units
        long gbase = (long)(m0 + c * 32 + row) * NOUT + n0;
        #pragma unroll
        for (int k = 0; k < 4; ++k) {          // 8 lanes x 16B = full 128B line/instr
            f32x4 v = *(const f32x4*)&Ep[row][c4 + k * 32];
            __builtin_nontemporal_store(v, (f32x4*)&C[gbase + c4 + k * 32]);
        }
    }
}

extern "C" void kernel_launch(void* const* d_in, const int* in_sizes, int n_in,
                              void* d_out, int out_size, void* d_ws, size_t ws_size,
                              hipStream_t stream) {
    const int*   nodes    = (const int*)d_in[0];
    const int*   adj      = (const int*)d_in[1];
    const float* features = (const float*)d_in[2];
    const float* lw       = (const float*)d_in[3];
    float*       out      = (float*)d_out;

    const size_t fbf_elems  = (size_t)NUM_NODES * FEAT_DIM;
    const size_t feat_elems = (size_t)NROWS * FEAT_DIM;
    const size_t need = (fbf_elems + feat_elems + (size_t)NOUT * FEAT_DIM) * 2;

    if (ws_size >= need) {
        unsigned short* fbf  = (unsigned short*)d_ws;
        unsigned short* feat = fbf + fbf_elems;
        unsigned short* wb   = feat + feat_elems;

        cvt_kernel<<<FBLK + (NOUT * FEAT_DIM) / (256 * 4), 256, 0, stream>>>(features, fbf, lw, wb);
        agg_sliced<<<(NROWS / 64) * NSLICE, 256, 0, stream>>>(nodes, adj, fbf, feat);
        gemm_kernel<<<1280, 256, 0, stream>>>(feat, wb, out);
    } else {
        unsigned short* feat = (unsigned short*)d_ws;
        unsigned short* wb   = feat + feat_elems;

        wcvt_kernel<<<(NOUT * FEAT_DIM) / (256 * 4), 256, 0, stream>>>(lw, wb);
        agg_f32_kernel<<<NROWS, 256, 0, stream>>>(nodes, adj, features, feat);
        gemm_kernel<<<1280, 256, 0, stream>>>(feat, wb, out);
    }
}

// Round 12
// 78.543 us; speedup vs baseline: 2.1237x; 1.0642x over previous
//
#include <hip/hip_runtime.h>

#define FEAT_DIM 256
#define K_NEIGH  32
#define NROWS    20480   // B*S = 2048*10
#define NOUT     1024    // CLIPS*DIM = 8*128
#define NUM_NODES 50000
#define SLICE_DIM 32
#define NSLICE    8
#define FBLK      1563   // ceil(NUM_NODES/32)
#define WBLK      256    // weight-convert blocks
#define REPN      196    // ceil(NUM_NODES/256) rep-init blocks

typedef __attribute__((ext_vector_type(8))) short bf16x8;
typedef __attribute__((ext_vector_type(4))) float f32x4;
typedef __attribute__((ext_vector_type(4))) int   i32x4;

__device__ __forceinline__ unsigned short f2bf(float f) {
    unsigned int u = __builtin_bit_cast(unsigned int, f);
    u += 0x7fffu + ((u >> 16) & 1u);
    return (unsigned short)(u >> 16);
}
__device__ __forceinline__ float bf2f(unsigned short h) {
    unsigned int u = ((unsigned int)h) << 16;
    return __builtin_bit_cast(float, u);
}
__device__ __forceinline__ void gload16(const void* g, void* l) {
    __builtin_amdgcn_global_load_lds(
        (const __attribute__((address_space(1))) unsigned int*)g,
        (__attribute__((address_space(3))) unsigned int*)l, 16, 0, 0);
}

// ---- convert: features -> fb[8][50000][32]  +  W -> bf16  +  rep init -------
__global__ __launch_bounds__(256) void cvt_kernel(const float* __restrict__ f,
                                                  unsigned short* __restrict__ fb,
                                                  const float* __restrict__ w,
                                                  unsigned short* __restrict__ wb,
                                                  int* __restrict__ rep) {
    int b = blockIdx.x;
    int t = threadIdx.x;
    if (b < FBLK) {
        int g = t >> 5;            // slice 0..7
        int i = t & 31;            // node offset
        int node = b * 32 + i;
        if (node >= NUM_NODES) return;
        const float* src = f + (long)node * FEAT_DIM + g * SLICE_DIM;
        unsigned short o[32];
        #pragma unroll
        for (int j = 0; j < 32; j += 4) {
            float4 v = *(const float4*)(src + j);
            o[j] = f2bf(v.x); o[j+1] = f2bf(v.y); o[j+2] = f2bf(v.z); o[j+3] = f2bf(v.w);
        }
        unsigned short* dst = fb + ((long)g * NUM_NODES + node) * SLICE_DIM;
        #pragma unroll
        for (int j = 0; j < 4; ++j)
            *(bf16x8*)(dst + j * 8) = *(const bf16x8*)(o + j * 8);
    } else if (b < FBLK + WBLK) {
        int i = ((b - FBLK) * 256 + t) * 4;
        float4 v = *(const float4*)(w + i);
        ushort4 o;
        o.x = f2bf(v.x); o.y = f2bf(v.y); o.z = f2bf(v.z); o.w = f2bf(v.w);
        *(ushort4*)(wb + i) = o;
    } else {
        int idx = (b - FBLK - WBLK) * 256 + t;
        if (idx < NUM_NODES) rep[idx] = 0x7fffffff;
    }
}

// ---- representative-row map: rep[node] = min row with that node --------------
__global__ __launch_bounds__(256) void minmap_kernel(const int* __restrict__ nodes,
                                                     int* __restrict__ rep) {
    int i = blockIdx.x * 256 + threadIdx.x;   // exactly NROWS threads
    atomicMin(&rep[nodes[i]], i);             // deterministic (min-reduce)
}

// ---- agg, XCD-sliced + unique-row dedup --------------------------------------
__global__ __launch_bounds__(256) void agg_dedup(const int* __restrict__ nodes,
                                                 const int* __restrict__ adj,
                                                 const unsigned short* __restrict__ fb,
                                                 const int* __restrict__ rep,
                                                 unsigned short* __restrict__ feat) {
    int slice = blockIdx.x & 7;
    int chunk = blockIdx.x >> 3;
    int t = threadIdx.x;
    int row = chunk * 64 + (t >> 2);
    int d8 = (t & 3) * 8;
    int node = nodes[row];
    if (rep[node] != row) return;             // duplicate row: gemm redirects
    const int* arow = adj + (long)node * K_NEIGH;
    int nbr[K_NEIGH];
    #pragma unroll
    for (int kk = 0; kk < K_NEIGH / 4; ++kk) {
        i32x4 q = *(const i32x4*)(arow + kk * 4);
        nbr[kk*4] = q.x; nbr[kk*4+1] = q.y; nbr[kk*4+2] = q.z; nbr[kk*4+3] = q.w;
    }
    const unsigned short* base = fb + (long)slice * NUM_NODES * SLICE_DIM + d8;
    float acc[8] = {};
    #pragma unroll
    for (int k = 0; k < K_NEIGH; ++k) {
        bf16x8 v = *(const bf16x8*)(base + (long)nbr[k] * SLICE_DIM);
        #pragma unroll
        for (int j = 0; j < 8; ++j) acc[j] += bf2f((unsigned short)v[j]);
    }
    unsigned short o[8];
    #pragma unroll
    for (int j = 0; j < 8; ++j) o[j] = f2bf(acc[j] * (1.0f / K_NEIGH));
    *(bf16x8*)(feat + (long)row * FEAT_DIM + slice * SLICE_DIM + d8) = *(const bf16x8*)o;
}

// ---- GEMM: C = relu(feat x W^T); A rows redirected via rep[]; plain stores --
__global__ __launch_bounds__(256) void gemm_kernel(const unsigned short* __restrict__ A,
                                                   const unsigned short* __restrict__ Bw,
                                                   const int* __restrict__ nodes,
                                                   const int* __restrict__ rep,
                                                   float* __restrict__ C) {
    __shared__ short As[2][128 * 32];
    __shared__ short Bs[2][128 * 32];

    int bid = blockIdx.x;
    int xcd = bid & 7;
    int i2 = bid >> 3;
    int mt = xcd * 20 + (i2 % 20);
    int nt = i2 / 20;

    int t = threadIdx.x;
    int wave = t >> 6, lane = t & 63;
    int wm = wave >> 1, wn = wave & 1;
    int m0 = mt * 128, n0 = nt * 128;
    int lr = lane & 15;
    int lk = (lane >> 4) * 8;

    int srow = t >> 2;
    int sseg = (t & 3) * 8;
    int r0 = srow, r1 = 64 + srow;
    if (rep) {                                  // redirect to representative rows
        r0 = rep[nodes[m0 + srow]];
        r1 = rep[nodes[m0 + 64 + srow]];
    } else {
        r0 = m0 + srow; r1 = m0 + 64 + srow;
    }
    const short* Ag0 = (const short*)A + (long)r0 * FEAT_DIM + sseg;
    const short* Ag1 = (const short*)A + (long)r1 * FEAT_DIM + sseg;
    const short* Bg  = (const short*)Bw + (long)(n0 + srow) * FEAT_DIM + sseg;

    f32x4 acc[4][4] = {};

#define STAGE(bufi, kb) do {                                         \
    gload16(Ag0 + (kb), &As[bufi][t * 8]);                           \
    gload16(Ag1 + (kb), &As[bufi][64 * 32 + t * 8]);                 \
    gload16(Bg + (kb), &Bs[bufi][t * 8]);                            \
    gload16(Bg + 64 * FEAT_DIM + (kb), &Bs[bufi][64 * 32 + t * 8]);  \
} while (0)

    STAGE(0, 0);
    asm volatile("s_waitcnt vmcnt(0)" ::: "memory");
    __builtin_amdgcn_s_barrier();

    #pragma unroll
    for (int it = 0; it < 8; ++it) {
        int cur = it & 1;
        if (it < 7) STAGE(cur ^ 1, (it + 1) * 32);

        bf16x8 a[4], b[4];
        #pragma unroll
        for (int i = 0; i < 4; ++i)
            a[i] = *(const bf16x8*)(&As[cur][(wm * 64 + i * 16 + lr) * 32 + lk]);
        #pragma unroll
        for (int j = 0; j < 4; ++j)
            b[j] = *(const bf16x8*)(&Bs[cur][(wn * 64 + j * 16 + lr) * 32 + lk]);
        #pragma unroll
        for (int i = 0; i < 4; ++i)
            #pragma unroll
            for (int j = 0; j < 4; ++j)
                acc[i][j] = __builtin_amdgcn_mfma_f32_16x16x32_bf16(a[i], b[j], acc[i][j], 0, 0, 0);

        if (it < 7) {
            asm volatile("s_waitcnt vmcnt(0)" ::: "memory");
            __builtin_amdgcn_s_barrier();
        }
    }
#undef STAGE

    // plain stores (no nt): L2 write-allocate merges 64B quarters to full lines
    int crow0 = m0 + wm * 64 + (lane >> 4) * 4;
    int ccol0 = n0 + wn * 64 + lr;
    #pragma unroll
    for (int i = 0; i < 4; ++i)
        #pragma unroll
        for (int j = 0; j < 4; ++j)
            #pragma unroll
            for (int r = 0; r < 4; ++r) {
                float v = acc[i][j][r];
                C[(long)(crow0 + i * 16 + r) * NOUT + ccol0 + j * 16] = v > 0.f ? v : 0.f;
            }
}

// ---- fallback-path kernels (small ws) ----------------------------------------
__global__ __launch_bounds__(256) void wcvt_kernel(const float* __restrict__ w,
                                                   unsigned short* __restrict__ wb) {
    int i = (blockIdx.x * 256 + threadIdx.x) * 4;
    float4 v = *(const float4*)(w + i);
    ushort4 o;
    o.x = f2bf(v.x); o.y = f2bf(v.y); o.z = f2bf(v.z); o.w = f2bf(v.w);
    *(ushort4*)(wb + i) = o;
}

__global__ __launch_bounds__(256) void agg_f32_kernel(const int* __restrict__ nodes,
                                                      const int* __restrict__ adj,
                                                      const float* __restrict__ features,
                                                      unsigned short* __restrict__ feat) {
    int row = blockIdx.x;
    int t = threadIdx.x;
    int node = nodes[row];
    const int* arow = adj + (long)node * K_NEIGH;
    float acc = 0.f;
    #pragma unroll
    for (int k = 0; k < K_NEIGH; ++k) {
        long nb = arow[k];
        acc += features[nb * FEAT_DIM + t];
    }
    feat[(long)row * FEAT_DIM + t] = f2bf(acc * (1.0f / K_NEIGH));
}

extern "C" void kernel_launch(void* const* d_in, const int* in_sizes, int n_in,
                              void* d_out, int out_size, void* d_ws, size_t ws_size,
                              hipStream_t stream) {
    const int*   nodes    = (const int*)d_in[0];
    const int*   adj      = (const int*)d_in[1];
    const float* features = (const float*)d_in[2];
    const float* lw       = (const float*)d_in[3];
    float*       out      = (float*)d_out;

    const size_t fbf_elems  = (size_t)NUM_NODES * FEAT_DIM;
    const size_t feat_elems = (size_t)NROWS * FEAT_DIM;
    const size_t wb_elems   = (size_t)NOUT * FEAT_DIM;
    const size_t need = (fbf_elems + feat_elems + wb_elems) * 2 + (size_t)NUM_NODES * 4;

    if (ws_size >= need) {
        unsigned short* fbf  = (unsigned short*)d_ws;
        unsigned short* feat = fbf + fbf_elems;
        unsigned short* wb   = feat + feat_elems;
        int*            rep  = (int*)(wb + wb_elems);

        cvt_kernel<<<FBLK + WBLK + REPN, 256, 0, stream>>>(features, fbf, lw, wb, rep);
        minmap_kernel<<<NROWS / 256, 256, 0, stream>>>(nodes, rep);
        agg_dedup<<<(NROWS / 64) * NSLICE, 256, 0, stream>>>(nodes, adj, fbf, rep, feat);
        gemm_kernel<<<1280, 256, 0, stream>>>(feat, wb, nodes, rep, out);
    } else {
        unsigned short* feat = (unsigned short*)d_ws;
        unsigned short* wb   = feat + feat_elems;

        wcvt_kernel<<<(NOUT * FEAT_DIM) / (256 * 4), 256, 0, stream>>>(lw, wb);
        agg_f32_kernel<<<NROWS, 256, 0, stream>>>(nodes, adj, features, feat);
        gemm_kernel<<<1280, 256, 0, stream>>>(feat, wb, nodes, nullptr, out);
    }
}